// Round 13
// baseline (593.437 us; speedup 1.0000x reference)
//
#include <hip/hip_runtime.h>
#include <hip/hip_bf16.h>
#include <hip/hip_cooperative_groups.h>

namespace cg = cooperative_groups;

#define N_NODES 50000
#define N_EDGES 640000
#define D 128
#define SCAN_BLK 25          // ceil(50000 / 2048)
#define PSTRIDE 50048        // per-partition stride for deg8/cursor8
#define MEGA_BLOCKS 1024
#define MEGA_NT (MEGA_BLOCKS * 256)   // 262144 threads

typedef __bf16 bf16x8 __attribute__((ext_vector_type(8)));
typedef float f32x4 __attribute__((ext_vector_type(4)));

__device__ __forceinline__ ushort f2bf(float f) {
    __hip_bfloat16 h = __float2bfloat16(f);
    return *(ushort*)&h;
}
__device__ __forceinline__ float bflo(uint u) { return __uint_as_float(u << 16); }
__device__ __forceinline__ float bfhi(uint u) { return __uint_as_float(u & 0xffff0000u); }

// -------- cooperative mega-kernel: zero+conv | hist+rank | scan1 | scan2 | fill --------
__global__ __launch_bounds__(256) void mega_kernel(const float* __restrict__ x,
                                                   const float* __restrict__ W1l,
                                                   const float* __restrict__ W1r,
                                                   const float* __restrict__ W2l,
                                                   const float* __restrict__ W2r,
                                                   const int* __restrict__ src,
                                                   const int* __restrict__ dst,
                                                   ushort* __restrict__ xb,
                                                   ushort* __restrict__ Wb1,
                                                   ushort* __restrict__ Wb2,
                                                   int* __restrict__ deg8,
                                                   int* __restrict__ rank,
                                                   int* __restrict__ incl,
                                                   int* __restrict__ blockSum,
                                                   int* __restrict__ row_off,
                                                   int* __restrict__ cursor8,
                                                   int* __restrict__ esrc) {
    cg::grid_group grid = cg::this_grid();
    __shared__ int wsum[4];
    const int tid = threadIdx.x;
    const int b = blockIdx.x;
    const int gtid = b * 256 + tid;

    // ---- phase 1: zero deg8 + convx (x->bf16) + convw (pack weights) ----
    if (gtid < (8 * PSTRIDE) / 4)      // 100096 uint4
        ((uint4*)deg8)[gtid] = make_uint4(0u, 0u, 0u, 0u);
    for (int i = gtid; i < (N_NODES * D) / 8; i += MEGA_NT) {   // 800000 units
        const float4 u0 = *(const float4*)&x[i * 8];
        const float4 u1 = *(const float4*)&x[i * 8 + 4];
        union { ushort u[8]; uint4 v; } p;
        p.u[0] = f2bf(u0.x); p.u[1] = f2bf(u0.y); p.u[2] = f2bf(u0.z); p.u[3] = f2bf(u0.w);
        p.u[4] = f2bf(u1.x); p.u[5] = f2bf(u1.y); p.u[6] = f2bf(u1.z); p.u[7] = f2bf(u1.w);
        *(uint4*)&xb[i * 8] = p.v;
    }
    if (gtid < 65536) {
        int i = gtid;
        if (i < 32768) {
            int n = i >> 8, k = i & 255;
            float v = (k < 128) ? W1l[n * 128 + k] : W1r[n * 128 + (k - 128)];
            Wb1[i] = f2bf(v);
        } else {
            int j = i - 32768;
            int n = j >> 8, k = j & 255;
            float v = (k < 128) ? W2l[n * 128 + k] : W2r[n * 128 + (k - 128)];
            Wb2[j] = f2bf(v);
        }
    }
    grid.sync();

    // ---- phase 2: hist + rank (XCD-private partitions keyed by blockIdx&7) ----
    {
        int* dp = deg8 + (b & 7) * PSTRIDE;
        for (int e = gtid; e < N_EDGES; e += MEGA_NT)
            rank[e] = atomicAdd(&dp[dst[e]], 1);
    }
    grid.sync();

    // ---- phase 3: scan1 — per-block inclusive scan of total deg (25 blocks) ----
    if (b < SCAN_BLK) {
        const int base = b * 2048 + tid * 8;
        int v[8];
        int s = 0;
#pragma unroll
        for (int i = 0; i < 8; ++i) {
            int idx = base + i;
            int tot = 0;
            if (idx < N_NODES) {
#pragma unroll
                for (int p = 0; p < 8; ++p) tot += deg8[p * PSTRIDE + idx];
            }
            v[i] = tot;
            s += tot;
        }
        const int lane = tid & 63;
        const int wid = tid >> 6;
        int ps = s;
#pragma unroll
        for (int off = 1; off < 64; off <<= 1) {
            int u = __shfl_up(ps, off, 64);
            if (lane >= off) ps += u;
        }
        if (lane == 63) wsum[wid] = ps;
        __syncthreads();
        int wOff = 0;
        for (int w = 0; w < wid; ++w) wOff += wsum[w];
        int run = wOff + ps - s;
#pragma unroll
        for (int i = 0; i < 8; ++i) {
            run += v[i];
            int idx = base + i;
            if (idx < N_NODES) incl[idx] = run;
        }
        if (tid == 255) blockSum[b] = wOff + ps;
    }
    grid.sync();

    // ---- phase 4: scan2 — add block prefix, emit row_off + partition starts ----
    if (b < SCAN_BLK) {
        int off = 0;
        for (int i = 0; i < b; ++i) off += blockSum[i];
#pragma unroll
        for (int i = 0; i < 8; ++i) {
            int idx = b * 2048 + i * 256 + tid;     // coalesced
            if (idx < N_NODES) {
                int inc = incl[idx] + off;
                row_off[idx + 1] = inc;
                int dp[8];
                int dsum = 0;
#pragma unroll
                for (int p = 0; p < 8; ++p) { dp[p] = deg8[p * PSTRIDE + idx]; dsum += dp[p]; }
                int c = inc - dsum;
#pragma unroll
                for (int p = 0; p < 8; ++p) { cursor8[p * PSTRIDE + idx] = c; c += dp[p]; }
            }
        }
        if (b == 0 && tid == 0) row_off[0] = 0;
    }
    grid.sync();

    // ---- phase 5: fill — esrc[start + rank] = src (no atomics) ----
    {
        const int* cp = cursor8 + (b & 7) * PSTRIDE;   // same key as phase 2
        for (int e = gtid; e < N_EDGES; e += MEGA_NT)
            esrc[cp[dst[e]] + rank[e]] = src[e];
    }
}

// -------- gather + mean (bf16): one wave per node, shfl-distributed indices --------
// lane = g*16 + c : edge-slot g (0..3), 16B chunk c (0..15) of the 256B row.
__global__ __launch_bounds__(256) void gather_mean(const int* __restrict__ row_off,
                                                   const int* __restrict__ esrc,
                                                   const ushort* __restrict__ feat,
                                                   ushort* __restrict__ mean) {
    const int node = (blockIdx.x * 256 + threadIdx.x) >> 6;
    const int lane = threadIdx.x & 63;
    if (node >= N_NODES) return;
    const int beg = row_off[node];
    const int end = row_off[node + 1];
    const int g = lane >> 4;           // edge sub-slot
    const int c = lane & 15;           // 16B chunk
    const char* fb = (const char*)feat;
    float acc[8];
#pragma unroll
    for (int r = 0; r < 8; ++r) acc[r] = 0.0f;

    for (int base = beg; base < end; base += 64) {
        const int lim = min(end - base, 64);
        int myIdx = 0;
        if (lane < lim) myIdx = esrc[base + lane];     // one coalesced load / 64 edges
        for (int i0 = 0; i0 < lim; i0 += 16) {
            uint4 v[4];
#pragma unroll
            for (int u = 0; u < 4; ++u) {
                int slot = i0 + u * 4 + g;
                int s = __shfl(myIdx, slot, 64);
                v[u] = make_uint4(0u, 0u, 0u, 0u);
                if (slot < lim)
                    v[u] = *(const uint4*)(fb + ((size_t)s << 8) + c * 16);
            }
#pragma unroll
            for (int u = 0; u < 4; ++u) {
                acc[0] += bflo(v[u].x);
                acc[1] += bfhi(v[u].x);
                acc[2] += bflo(v[u].y);
                acc[3] += bfhi(v[u].y);
                acc[4] += bflo(v[u].z);
                acc[5] += bfhi(v[u].z);
                acc[6] += bflo(v[u].w);
                acc[7] += bfhi(v[u].w);
            }
        }
    }
#pragma unroll
    for (int r = 0; r < 8; ++r) {
        acc[r] += __shfl_xor(acc[r], 16, 64);
        acc[r] += __shfl_xor(acc[r], 32, 64);
    }
    if (g == 0) {
        const int dg = end - beg;
        const float inv = (dg > 0) ? 1.0f / (float)dg : 0.0f;
        union { ushort u[8]; uint4 v; } p;
#pragma unroll
        for (int r = 0; r < 8; ++r) p.u[r] = f2bf(acc[r] * inv);
        *(uint4*)((char*)mean + ((size_t)node << 8) + c * 16) = p.v;
    }
}

// -------- fused MFMA: out = relu( [mean|feat](bf16) @ Wb^T + b ) --------
// Block: 256 threads (4 waves), tile 64 nodes x 128 outs, K = 256.
// Wave w owns cols [w*32, w*32+32): acc[4 mfrag][2 nfrag].
// A staged in LDS bf16, XOR-swizzled: byte ^= (row&7)<<4.
template <int OUT_BF16>
__global__ __launch_bounds__(256) void sage_mfma(const ushort* __restrict__ feat,
                                                 const ushort* __restrict__ mean,
                                                 const ushort* __restrict__ Wb,
                                                 const float* __restrict__ bias,
                                                 void* __restrict__ outv) {
    __shared__ __align__(16) char As[64 * 512];   // 64 rows x 256 bf16, swizzled

    const int tid = threadIdx.x;
    const int nodeBase = blockIdx.x * 64;

    // ---- stage: bf16 rows -> swizzled LDS ----
    {
        const int row = tid >> 2;          // 0..63
        const int q = tid & 3;             // 128-byte quarter of the 512B row
        const int node = nodeBase + row;
        const bool valid = node < N_NODES;
        const ushort* srcp = (q < 2) ? (mean + (size_t)node * D + q * 64)
                                     : (feat + (size_t)node * D + (q - 2) * 64);
        const int swz = (row & 7) << 4;
#pragma unroll
        for (int c = 0; c < 8; ++c) {      // 8 chunks of 16 B
            uint4 v = make_uint4(0u, 0u, 0u, 0u);
            if (valid) v = *(const uint4*)(srcp + c * 8);
            int colb = q * 128 + c * 16;   // byte col
            *(uint4*)(As + row * 512 + (colb ^ swz)) = v;
        }
    }
    __syncthreads();

    // ---- MFMA main loop ----
    const int lane = tid & 63;
    const int w = tid >> 6;            // wave id: col slice w*32
    const int l15 = lane & 15;
    const int lg = lane >> 4;          // k-group
    const int swz = (l15 & 7) << 4;

    f32x4 acc[4][2];
#pragma unroll
    for (int m = 0; m < 4; ++m) {
        acc[m][0] = (f32x4)(0.0f);
        acc[m][1] = (f32x4)(0.0f);
    }

    const ushort* WA = Wb + (size_t)(w * 32 + l15) * 256 + lg * 8;
    const ushort* WB = WA + 16 * 256;

#pragma unroll
    for (int t = 0; t < 8; ++t) {      // k0 = t*32
        bf16x8 b0 = *(const bf16x8*)(WA + t * 32);
        bf16x8 b1 = *(const bf16x8*)(WB + t * 32);
        const int kb = t * 64 + lg * 16;                   // byte col base
#pragma unroll
        for (int m = 0; m < 4; ++m) {
            bf16x8 a = *(const bf16x8*)(As + (m * 16 + l15) * 512 + (kb ^ swz));
            acc[m][0] = __builtin_amdgcn_mfma_f32_16x16x32_bf16(a, b0, acc[m][0], 0, 0, 0);
            acc[m][1] = __builtin_amdgcn_mfma_f32_16x16x32_bf16(a, b1, acc[m][1], 0, 0, 0);
        }
    }

    // ---- epilogue: bias + relu + store ----
    const int c0 = w * 32 + l15;
    const float bv0 = bias[c0];
    const float bv1 = bias[c0 + 16];
#pragma unroll
    for (int m = 0; m < 4; ++m) {
#pragma unroll
        for (int j = 0; j < 4; ++j) {
            int node = nodeBase + m * 16 + lg * 4 + j;
            if (node < N_NODES) {
                float r0 = fmaxf(acc[m][0][j] + bv0, 0.0f);
                float r1 = fmaxf(acc[m][1][j] + bv1, 0.0f);
                if (OUT_BF16) {
                    ushort* out = (ushort*)outv;
                    out[(size_t)node * D + c0]      = f2bf(r0);
                    out[(size_t)node * D + c0 + 16] = f2bf(r1);
                } else {
                    float* out = (float*)outv;
                    out[(size_t)node * D + c0]      = r0;
                    out[(size_t)node * D + c0 + 16] = r1;
                }
            }
        }
    }
}

extern "C" void kernel_launch(void* const* d_in, const int* in_sizes, int n_in,
                              void* d_out, int out_size, void* d_ws, size_t ws_size,
                              hipStream_t stream) {
    const float* x   = (const float*)d_in[0];
    const int*   ei  = (const int*)d_in[1];   // jax x64 disabled -> int32
    const int*   src = ei;
    const int*   dst = ei + N_EDGES;
    const float* W1l = (const float*)d_in[2];
    const float* b1  = (const float*)d_in[3];
    const float* W1r = (const float*)d_in[4];
    const float* W2l = (const float*)d_in[5];
    const float* b2  = (const float*)d_in[6];
    const float* W2r = (const float*)d_in[7];
    float* out = (float*)d_out;

    ushort* xb     = (ushort*)d_ws;                        // N*D bf16
    ushort* hb     = xb + (size_t)N_NODES * D;             // N*D bf16
    ushort* meanb  = hb + (size_t)N_NODES * D;             // N*D bf16
    int*   row_off = (int*)(meanb + (size_t)N_NODES * D);  // N+1
    int*   esrc    = row_off + (N_NODES + 1);              // E
    int*   rank    = esrc + N_EDGES;                       // E
    int*   deg8    = rank + N_EDGES;                       // 8*PSTRIDE
    int*   cursor8 = deg8 + 8 * PSTRIDE;                   // 8*PSTRIDE
    int*   incl    = cursor8 + 8 * PSTRIDE;                // N
    int*   blockSum= incl + N_NODES;                       // SCAN_BLK
    ushort* Wb1    = (ushort*)(blockSum + SCAN_BLK);       // 128*256 bf16
    ushort* Wb2    = Wb1 + 128 * 256;                      // 128*256 bf16

    const int waveBlocks = (N_NODES * 64 + 255) / 256;     // 12500
    const int gemmBlocks = (N_NODES + 63) / 64;            // 782

    // ---- CSR build + converts: ONE cooperative launch ----
    {
        void* args[] = {
            (void*)&x, (void*)&W1l, (void*)&W1r, (void*)&W2l, (void*)&W2r,
            (void*)&src, (void*)&dst,
            (void*)&xb, (void*)&Wb1, (void*)&Wb2,
            (void*)&deg8, (void*)&rank, (void*)&incl, (void*)&blockSum,
            (void*)&row_off, (void*)&cursor8, (void*)&esrc
        };
        hipLaunchCooperativeKernel((void*)mega_kernel, dim3(MEGA_BLOCKS), dim3(256),
                                   args, 0, stream);
    }

    // ---- layer 1 ----
    gather_mean<<<waveBlocks, 256, 0, stream>>>(row_off, esrc, xb, meanb);
    sage_mfma<1><<<gemmBlocks, 256, 0, stream>>>(xb, meanb, Wb1, b1, hb);

    // ---- layer 2 ----
    gather_mean<<<waveBlocks, 256, 0, stream>>>(row_off, esrc, hb, meanb);
    sage_mfma<0><<<gemmBlocks, 256, 0, stream>>>(hb, meanb, Wb2, b2, out);
}

// Round 14
// 167.264 us; speedup vs baseline: 3.5479x; 3.5479x over previous
//
#include <hip/hip_runtime.h>
#include <hip/hip_bf16.h>

#define N_NODES 50000
#define N_EDGES 640000
#define D 128
#define SCAN_BLK 25          // ceil(50000 / 2048)
#define PSTRIDE 50048        // per-partition stride for deg8/cursor8

typedef __bf16 bf16x8 __attribute__((ext_vector_type(8)));
typedef float f32x4 __attribute__((ext_vector_type(4)));

__device__ __forceinline__ ushort f2bf(float f) {
    __hip_bfloat16 h = __float2bfloat16(f);
    return *(ushort*)&h;
}
__device__ __forceinline__ float bflo(uint u) { return __uint_as_float(u << 16); }
__device__ __forceinline__ float bfhi(uint u) { return __uint_as_float(u & 0xffff0000u); }

// -------- zero deg8 + scanState: 16B/thread, bounds-checked --------
// covers 8*PSTRIDE ints (deg8) + 32 ints (scanState) = 100104 uint4
__global__ __launch_bounds__(256) void zero_kernel(uint4* __restrict__ p) {
    int i = blockIdx.x * 256 + threadIdx.x;
    if (i < (8 * PSTRIDE + 32) / 4)
        p[i] = make_uint4(0u, 0u, 0u, 0u);
}

// -------- prep: hist+rank (XCD-private) + convx + convw, fused --------
// blocks [0,625): rank[e] = deg8[(b&7)][dst[e]]++ over 1024 edges each
// blocks [625,3750): x->xb bf16 (8 elems/thread)
// blocks [3750,4006): pack W1/W2 into Wb1/Wb2
__global__ __launch_bounds__(256) void prep_kernel(const float* __restrict__ x,
                                                   const float* __restrict__ W1l,
                                                   const float* __restrict__ W1r,
                                                   const float* __restrict__ W2l,
                                                   const float* __restrict__ W2r,
                                                   const int* __restrict__ dst,
                                                   ushort* __restrict__ xb,
                                                   ushort* __restrict__ Wb1,
                                                   ushort* __restrict__ Wb2,
                                                   int* __restrict__ deg8,
                                                   int* __restrict__ rank) {
    const int b = blockIdx.x;
    const int tid = threadIdx.x;
    if (b < 625) {
        const int base = b * 1024 + tid;
        int* dp = deg8 + (b & 7) * PSTRIDE;
        int d0 = dst[base];
        int d1 = dst[base + 256];
        int d2 = dst[base + 512];
        int d3 = dst[base + 768];
        int r0 = atomicAdd(&dp[d0], 1);
        int r1 = atomicAdd(&dp[d1], 1);
        int r2 = atomicAdd(&dp[d2], 1);
        int r3 = atomicAdd(&dp[d3], 1);
        rank[base]       = r0;
        rank[base + 256] = r1;
        rank[base + 512] = r2;
        rank[base + 768] = r3;
    } else if (b < 3750) {
        int i = (b - 625) * 256 + tid;
        const float4 u0 = *(const float4*)&x[i * 8];
        const float4 u1 = *(const float4*)&x[i * 8 + 4];
        union { ushort u[8]; uint4 v; } p;
        p.u[0] = f2bf(u0.x); p.u[1] = f2bf(u0.y); p.u[2] = f2bf(u0.z); p.u[3] = f2bf(u0.w);
        p.u[4] = f2bf(u1.x); p.u[5] = f2bf(u1.y); p.u[6] = f2bf(u1.z); p.u[7] = f2bf(u1.w);
        *(uint4*)&xb[i * 8] = p.v;
    } else {
        int i = (b - 3750) * 256 + tid;     // [0, 65536)
        if (i < 32768) {
            int n = i >> 8, k = i & 255;
            float v = (k < 128) ? W1l[n * 128 + k] : W1r[n * 128 + (k - 128)];
            Wb1[i] = f2bf(v);
        } else {
            int j = i - 32768;
            int n = j >> 8, k = j & 255;
            float v = (k < 128) ? W2l[n * 128 + k] : W2r[n * 128 + (k - 128)];
            Wb2[j] = f2bf(v);
        }
    }
}

// -------- fused scan (chained, decoupled lookback over 25 blocks) --------
// Computes total degree per node, global prefix, and emits row_off + per-partition
// start cursors in ONE dispatch. Block b publishes (incl<<1)|1 into scanState[b]
// (device-scope atomicExch); block b+1 spins on atomicAdd(state,0). Blocks
// dispatch in index order -> forward progress guaranteed (standard chained scan).
__global__ __launch_bounds__(256) void scan_kernel(const int* __restrict__ deg8,
                                                   int* __restrict__ scanState,
                                                   int* __restrict__ row_off,
                                                   int* __restrict__ cursor8) {
    __shared__ int wsum[4];
    __shared__ int sExcl;
    const int b = blockIdx.x;
    const int t = threadIdx.x;
    const int base = b * 2048 + t * 8;

    int v[8];
    int s = 0;
#pragma unroll
    for (int i = 0; i < 8; ++i) {
        int idx = base + i;
        int tot = 0;
        if (idx < N_NODES) {
#pragma unroll
            for (int p = 0; p < 8; ++p) tot += deg8[p * PSTRIDE + idx];
        }
        v[i] = tot;
        s += tot;
    }
    const int lane = t & 63;
    const int wid = t >> 6;
    int ps = s;
#pragma unroll
    for (int off = 1; off < 64; off <<= 1) {
        int u = __shfl_up(ps, off, 64);
        if (lane >= off) ps += u;
    }
    if (lane == 63) wsum[wid] = ps;
    __syncthreads();
    int wOff = 0;
    for (int w = 0; w < wid; ++w) wOff += wsum[w];
    const int total = wsum[0] + wsum[1] + wsum[2] + wsum[3];

    if (t == 0) {
        int excl = 0;
        if (b > 0) {
            int st;
            do { st = atomicAdd(&scanState[b - 1], 0); } while ((st & 1) == 0);
            excl = st >> 1;
        }
        atomicExch(&scanState[b], ((excl + total) << 1) | 1);
        sExcl = excl;
    }
    __syncthreads();
    const int excl = sExcl;

    int run = excl + wOff + ps - s;   // exclusive prefix before this thread's elems
#pragma unroll
    for (int i = 0; i < 8; ++i) {
        run += v[i];                  // inclusive at idx
        int idx = base + i;
        if (idx < N_NODES) {
            row_off[idx + 1] = run;
            int c = run - v[i];       // start offset for partition 0
#pragma unroll
            for (int p = 0; p < 8; ++p) {
                cursor8[p * PSTRIDE + idx] = c;
                c += deg8[p * PSTRIDE + idx];
            }
        }
    }
    if (b == 0 && t == 0) row_off[0] = 0;
}

// -------- fill: esrc[start + rank] = src — NO atomics, pure loads+scatter --------
__global__ __launch_bounds__(256) void fill_kernel(const int* __restrict__ src,
                                                   const int* __restrict__ dst,
                                                   const int* __restrict__ rank,
                                                   const int* __restrict__ cursor8,
                                                   int* __restrict__ esrc) {
    const int base = blockIdx.x * 1024 + threadIdx.x;
    const int* cp = cursor8 + (blockIdx.x & 7) * PSTRIDE;
    int d0 = dst[base];
    int d1 = dst[base + 256];
    int d2 = dst[base + 512];
    int d3 = dst[base + 768];
    int s0 = src[base];
    int s1 = src[base + 256];
    int s2 = src[base + 512];
    int s3 = src[base + 768];
    int r0 = rank[base];
    int r1 = rank[base + 256];
    int r2 = rank[base + 512];
    int r3 = rank[base + 768];
    esrc[cp[d0] + r0] = s0;
    esrc[cp[d1] + r1] = s1;
    esrc[cp[d2] + r2] = s2;
    esrc[cp[d3] + r3] = s3;
}

// -------- gather + mean (bf16): one wave per node, shfl-distributed indices --------
// One coalesced esrc load per 64 edges; feat addresses via __shfl (single memory
// dependency at top, then all feat loads pipeline freely).
// lane = g*16 + c : edge-slot g (0..3), 16B chunk c (0..15) of the 256B row.
__global__ __launch_bounds__(256) void gather_mean(const int* __restrict__ row_off,
                                                   const int* __restrict__ esrc,
                                                   const ushort* __restrict__ feat,
                                                   ushort* __restrict__ mean) {
    const int node = (blockIdx.x * 256 + threadIdx.x) >> 6;
    const int lane = threadIdx.x & 63;
    if (node >= N_NODES) return;
    const int beg = row_off[node];
    const int end = row_off[node + 1];
    const int g = lane >> 4;           // edge sub-slot
    const int c = lane & 15;           // 16B chunk
    const char* fb = (const char*)feat;
    float acc[8];
#pragma unroll
    for (int r = 0; r < 8; ++r) acc[r] = 0.0f;

    for (int base = beg; base < end; base += 64) {
        const int lim = min(end - base, 64);
        int myIdx = 0;
        if (lane < lim) myIdx = esrc[base + lane];     // one coalesced load / 64 edges
        for (int i0 = 0; i0 < lim; i0 += 16) {
            uint4 v[4];
#pragma unroll
            for (int u = 0; u < 4; ++u) {
                int slot = i0 + u * 4 + g;
                int s = __shfl(myIdx, slot, 64);
                v[u] = make_uint4(0u, 0u, 0u, 0u);
                if (slot < lim)
                    v[u] = *(const uint4*)(fb + ((size_t)s << 8) + c * 16);
            }
#pragma unroll
            for (int u = 0; u < 4; ++u) {
                acc[0] += bflo(v[u].x);
                acc[1] += bfhi(v[u].x);
                acc[2] += bflo(v[u].y);
                acc[3] += bfhi(v[u].y);
                acc[4] += bflo(v[u].z);
                acc[5] += bfhi(v[u].z);
                acc[6] += bflo(v[u].w);
                acc[7] += bfhi(v[u].w);
            }
        }
    }
#pragma unroll
    for (int r = 0; r < 8; ++r) {
        acc[r] += __shfl_xor(acc[r], 16, 64);
        acc[r] += __shfl_xor(acc[r], 32, 64);
    }
    if (g == 0) {
        const int dg = end - beg;
        const float inv = (dg > 0) ? 1.0f / (float)dg : 0.0f;
        union { ushort u[8]; uint4 v; } p;
#pragma unroll
        for (int r = 0; r < 8; ++r) p.u[r] = f2bf(acc[r] * inv);
        *(uint4*)((char*)mean + ((size_t)node << 8) + c * 16) = p.v;
    }
}

// -------- fused MFMA: out = relu( [mean|feat](bf16) @ Wb^T + b ) --------
// Block: 256 threads (4 waves), tile 64 nodes x 128 outs, K = 256.
// Wave w owns cols [w*32, w*32+32): acc[4 mfrag][2 nfrag].
// A staged in LDS bf16, XOR-swizzled: byte ^= (row&7)<<4.
template <int OUT_BF16>
__global__ __launch_bounds__(256) void sage_mfma(const ushort* __restrict__ feat,
                                                 const ushort* __restrict__ mean,
                                                 const ushort* __restrict__ Wb,
                                                 const float* __restrict__ bias,
                                                 void* __restrict__ outv) {
    __shared__ __align__(16) char As[64 * 512];   // 64 rows x 256 bf16, swizzled

    const int tid = threadIdx.x;
    const int nodeBase = blockIdx.x * 64;

    // ---- stage: bf16 rows -> swizzled LDS ----
    {
        const int row = tid >> 2;          // 0..63
        const int q = tid & 3;             // 128-byte quarter of the 512B row
        const int node = nodeBase + row;
        const bool valid = node < N_NODES;
        const ushort* srcp = (q < 2) ? (mean + (size_t)node * D + q * 64)
                                     : (feat + (size_t)node * D + (q - 2) * 64);
        const int swz = (row & 7) << 4;
#pragma unroll
        for (int c = 0; c < 8; ++c) {      // 8 chunks of 16 B
            uint4 v = make_uint4(0u, 0u, 0u, 0u);
            if (valid) v = *(const uint4*)(srcp + c * 8);
            int colb = q * 128 + c * 16;   // byte col
            *(uint4*)(As + row * 512 + (colb ^ swz)) = v;
        }
    }
    __syncthreads();

    // ---- MFMA main loop ----
    const int lane = tid & 63;
    const int w = tid >> 6;            // wave id: col slice w*32
    const int l15 = lane & 15;
    const int lg = lane >> 4;          // k-group
    const int swz = (l15 & 7) << 4;

    f32x4 acc[4][2];
#pragma unroll
    for (int m = 0; m < 4; ++m) {
        acc[m][0] = (f32x4)(0.0f);
        acc[m][1] = (f32x4)(0.0f);
    }

    const ushort* WA = Wb + (size_t)(w * 32 + l15) * 256 + lg * 8;
    const ushort* WB = WA + 16 * 256;

#pragma unroll
    for (int t = 0; t < 8; ++t) {      // k0 = t*32
        bf16x8 b0 = *(const bf16x8*)(WA + t * 32);
        bf16x8 b1 = *(const bf16x8*)(WB + t * 32);
        const int kb = t * 64 + lg * 16;                   // byte col base
#pragma unroll
        for (int m = 0; m < 4; ++m) {
            bf16x8 a = *(const bf16x8*)(As + (m * 16 + l15) * 512 + (kb ^ swz));
            acc[m][0] = __builtin_amdgcn_mfma_f32_16x16x32_bf16(a, b0, acc[m][0], 0, 0, 0);
            acc[m][1] = __builtin_amdgcn_mfma_f32_16x16x32_bf16(a, b1, acc[m][1], 0, 0, 0);
        }
    }

    // ---- epilogue: bias + relu + store ----
    const int c0 = w * 32 + l15;
    const float bv0 = bias[c0];
    const float bv1 = bias[c0 + 16];
#pragma unroll
    for (int m = 0; m < 4; ++m) {
#pragma unroll
        for (int j = 0; j < 4; ++j) {
            int node = nodeBase + m * 16 + lg * 4 + j;
            if (node < N_NODES) {
                float r0 = fmaxf(acc[m][0][j] + bv0, 0.0f);
                float r1 = fmaxf(acc[m][1][j] + bv1, 0.0f);
                if (OUT_BF16) {
                    ushort* out = (ushort*)outv;
                    out[(size_t)node * D + c0]      = f2bf(r0);
                    out[(size_t)node * D + c0 + 16] = f2bf(r1);
                } else {
                    float* out = (float*)outv;
                    out[(size_t)node * D + c0]      = r0;
                    out[(size_t)node * D + c0 + 16] = r1;
                }
            }
        }
    }
}

extern "C" void kernel_launch(void* const* d_in, const int* in_sizes, int n_in,
                              void* d_out, int out_size, void* d_ws, size_t ws_size,
                              hipStream_t stream) {
    const float* x   = (const float*)d_in[0];
    const int*   ei  = (const int*)d_in[1];   // jax x64 disabled -> int32
    const int*   src = ei;
    const int*   dst = ei + N_EDGES;
    const float* W1l = (const float*)d_in[2];
    const float* b1  = (const float*)d_in[3];
    const float* W1r = (const float*)d_in[4];
    const float* W2l = (const float*)d_in[5];
    const float* b2  = (const float*)d_in[6];
    const float* W2r = (const float*)d_in[7];
    float* out = (float*)d_out;

    ushort* xb     = (ushort*)d_ws;                        // N*D bf16
    ushort* hb     = xb + (size_t)N_NODES * D;             // N*D bf16
    ushort* meanb  = hb + (size_t)N_NODES * D;             // N*D bf16
    int*   row_off = (int*)(meanb + (size_t)N_NODES * D);  // N+1
    int*   esrc    = row_off + (N_NODES + 1);              // E
    int*   rank    = esrc + N_EDGES;                       // E
    int*   deg8    = rank + N_EDGES;                       // 8*PSTRIDE
    int*   scanSt  = deg8 + 8 * PSTRIDE;                   // 32 (zeroed with deg8)
    int*   cursor8 = scanSt + 32;                          // 8*PSTRIDE
    ushort* Wb1    = (ushort*)(cursor8 + 8 * PSTRIDE);     // 128*256 bf16
    ushort* Wb2    = Wb1 + 128 * 256;                      // 128*256 bf16

    const int edge4Blocks = N_EDGES / 1024;                // 625 exact
    const int waveBlocks = (N_NODES * 64 + 255) / 256;     // 12500
    const int gemmBlocks = (N_NODES + 63) / 64;            // 782
    const int prepBlocks = 625 + 3125 + 256;               // 4006
    const int zeroBlocks = ((8 * PSTRIDE + 32) / 4 + 255) / 256;  // 392

    // ---- CSR build + converts (once; shared by both layers) ----
    zero_kernel<<<zeroBlocks, 256, 0, stream>>>((uint4*)deg8);
    prep_kernel<<<prepBlocks, 256, 0, stream>>>(x, W1l, W1r, W2l, W2r, dst,
                                                xb, Wb1, Wb2, deg8, rank);
    scan_kernel<<<SCAN_BLK, 256, 0, stream>>>(deg8, scanSt, row_off, cursor8);
    fill_kernel<<<edge4Blocks, 256, 0, stream>>>(src, dst, rank, cursor8, esrc);

    // ---- layer 1 ----
    gather_mean<<<waveBlocks, 256, 0, stream>>>(row_off, esrc, xb, meanb);
    sage_mfma<1><<<gemmBlocks, 256, 0, stream>>>(xb, meanb, Wb1, b1, hb);

    // ---- layer 2 ----
    gather_mean<<<waveBlocks, 256, 0, stream>>>(row_off, esrc, hb, meanb);
    sage_mfma<0><<<gemmBlocks, 256, 0, stream>>>(hb, meanb, Wb2, b2, out);
}

// Round 15
// 149.214 us; speedup vs baseline: 3.9771x; 1.1210x over previous
//
#include <hip/hip_runtime.h>
#include <hip/hip_bf16.h>

#define N_NODES 50000
#define N_EDGES 640000
#define D 128
#define SCAN_BLK 25          // ceil(50000 / 2048)
#define PSTRIDE 50048        // per-partition stride for deg8/cursor8

typedef __bf16 bf16x8 __attribute__((ext_vector_type(8)));
typedef float f32x4 __attribute__((ext_vector_type(4)));

__device__ __forceinline__ ushort f2bf(float f) {
    __hip_bfloat16 h = __float2bfloat16(f);
    return *(ushort*)&h;
}
__device__ __forceinline__ float bflo(uint u) { return __uint_as_float(u << 16); }
__device__ __forceinline__ float bfhi(uint u) { return __uint_as_float(u & 0xffff0000u); }

// -------- zero deg8: 16B/thread, exact cover --------
__global__ __launch_bounds__(256) void zero_kernel(uint4* __restrict__ p) {
    p[blockIdx.x * 256 + threadIdx.x] = make_uint4(0u, 0u, 0u, 0u);
}

// -------- prep: hist+rank (XCD-private) + convx + convw, fused --------
__global__ __launch_bounds__(256) void prep_kernel(const float* __restrict__ x,
                                                   const float* __restrict__ W1l,
                                                   const float* __restrict__ W1r,
                                                   const float* __restrict__ W2l,
                                                   const float* __restrict__ W2r,
                                                   const int* __restrict__ dst,
                                                   ushort* __restrict__ xb,
                                                   ushort* __restrict__ Wb1,
                                                   ushort* __restrict__ Wb2,
                                                   int* __restrict__ deg8,
                                                   int* __restrict__ rank) {
    const int b = blockIdx.x;
    const int tid = threadIdx.x;
    if (b < 625) {
        const int base = b * 1024 + tid;
        int* dp = deg8 + (b & 7) * PSTRIDE;
        int d0 = dst[base];
        int d1 = dst[base + 256];
        int d2 = dst[base + 512];
        int d3 = dst[base + 768];
        int r0 = atomicAdd(&dp[d0], 1);
        int r1 = atomicAdd(&dp[d1], 1);
        int r2 = atomicAdd(&dp[d2], 1);
        int r3 = atomicAdd(&dp[d3], 1);
        rank[base]       = r0;
        rank[base + 256] = r1;
        rank[base + 512] = r2;
        rank[base + 768] = r3;
    } else if (b < 3750) {
        int i = (b - 625) * 256 + tid;
        const float4 u0 = *(const float4*)&x[i * 8];
        const float4 u1 = *(const float4*)&x[i * 8 + 4];
        union { ushort u[8]; uint4 v; } p;
        p.u[0] = f2bf(u0.x); p.u[1] = f2bf(u0.y); p.u[2] = f2bf(u0.z); p.u[3] = f2bf(u0.w);
        p.u[4] = f2bf(u1.x); p.u[5] = f2bf(u1.y); p.u[6] = f2bf(u1.z); p.u[7] = f2bf(u1.w);
        *(uint4*)&xb[i * 8] = p.v;
    } else {
        int i = (b - 3750) * 256 + tid;     // [0, 65536)
        if (i < 32768) {
            int n = i >> 8, k = i & 255;
            float v = (k < 128) ? W1l[n * 128 + k] : W1r[n * 128 + (k - 128)];
            Wb1[i] = f2bf(v);
        } else {
            int j = i - 32768;
            int n = j >> 8, k = j & 255;
            float v = (k < 128) ? W2l[n * 128 + k] : W2r[n * 128 + (k - 128)];
            Wb2[j] = f2bf(v);
        }
    }
}

// -------- scan pass 1: per-block inclusive scan of total deg (2048/block) --------
__global__ __launch_bounds__(256) void scan1_kernel(const int* __restrict__ deg8,
                                                    int* __restrict__ incl,
                                                    int* __restrict__ blockSum) {
    __shared__ int wsum[4];
    const int t = threadIdx.x;
    const int base = blockIdx.x * 2048 + t * 8;
    int v[8];
    int s = 0;
#pragma unroll
    for (int i = 0; i < 8; ++i) {
        int idx = base + i;
        int tot = 0;
        if (idx < N_NODES) {
#pragma unroll
            for (int p = 0; p < 8; ++p) tot += deg8[p * PSTRIDE + idx];
        }
        v[i] = tot;
        s += tot;
    }
    const int lane = t & 63;
    const int wid = t >> 6;
    int ps = s;
#pragma unroll
    for (int off = 1; off < 64; off <<= 1) {
        int u = __shfl_up(ps, off, 64);
        if (lane >= off) ps += u;
    }
    if (lane == 63) wsum[wid] = ps;
    __syncthreads();
    int wOff = 0;
    for (int w = 0; w < wid; ++w) wOff += wsum[w];
    int run = wOff + ps - s;
#pragma unroll
    for (int i = 0; i < 8; ++i) {
        run += v[i];
        int idx = base + i;
        if (idx < N_NODES) incl[idx] = run;
    }
    if (t == 255) blockSum[blockIdx.x] = wOff + ps;
}

// -------- scan pass 2: add block prefix, emit row_off + per-partition start offsets --------
__global__ __launch_bounds__(256) void scan2_kernel(const int* __restrict__ deg8,
                                                    const int* __restrict__ incl,
                                                    const int* __restrict__ blockSum,
                                                    int* __restrict__ row_off,
                                                    int* __restrict__ cursor8) {
    const int b = blockIdx.x;
    int off = 0;
    for (int i = 0; i < b; ++i) off += blockSum[i];
    const int t = threadIdx.x;
#pragma unroll
    for (int i = 0; i < 8; ++i) {
        int idx = b * 2048 + i * 256 + t;     // coalesced
        if (idx < N_NODES) {
            int inc = incl[idx] + off;
            row_off[idx + 1] = inc;
            int dp[8];
            int dsum = 0;
#pragma unroll
            for (int p = 0; p < 8; ++p) { dp[p] = deg8[p * PSTRIDE + idx]; dsum += dp[p]; }
            int c = inc - dsum;
#pragma unroll
            for (int p = 0; p < 8; ++p) { cursor8[p * PSTRIDE + idx] = c; c += dp[p]; }
        }
    }
    if (b == 0 && t == 0) row_off[0] = 0;
}

// -------- fill: esrc[start + rank] = src — NO atomics, pure loads+scatter --------
__global__ __launch_bounds__(256) void fill_kernel(const int* __restrict__ src,
                                                   const int* __restrict__ dst,
                                                   const int* __restrict__ rank,
                                                   const int* __restrict__ cursor8,
                                                   int* __restrict__ esrc) {
    const int base = blockIdx.x * 1024 + threadIdx.x;
    const int* cp = cursor8 + (blockIdx.x & 7) * PSTRIDE;
    int d0 = dst[base];
    int d1 = dst[base + 256];
    int d2 = dst[base + 512];
    int d3 = dst[base + 768];
    int s0 = src[base];
    int s1 = src[base + 256];
    int s2 = src[base + 512];
    int s3 = src[base + 768];
    int r0 = rank[base];
    int r1 = rank[base + 256];
    int r2 = rank[base + 512];
    int r3 = rank[base + 768];
    esrc[cp[d0] + r0] = s0;
    esrc[cp[d1] + r1] = s1;
    esrc[cp[d2] + r2] = s2;
    esrc[cp[d3] + r3] = s3;
}

// -------- gather + mean (bf16): one wave per node, shfl-distributed indices --------
// One coalesced esrc load per 64 edges; feat addresses via __shfl (single memory
// dependency at top, then all feat loads pipeline freely).
// lane = g*16 + c : edge-slot g (0..3), 16B chunk c (0..15) of the 256B row.
__global__ __launch_bounds__(256) void gather_mean(const int* __restrict__ row_off,
                                                   const int* __restrict__ esrc,
                                                   const ushort* __restrict__ feat,
                                                   ushort* __restrict__ mean) {
    const int node = (blockIdx.x * 256 + threadIdx.x) >> 6;
    const int lane = threadIdx.x & 63;
    if (node >= N_NODES) return;
    const int beg = row_off[node];
    const int end = row_off[node + 1];
    const int g = lane >> 4;           // edge sub-slot
    const int c = lane & 15;           // 16B chunk
    const char* fb = (const char*)feat;
    float acc[8];
#pragma unroll
    for (int r = 0; r < 8; ++r) acc[r] = 0.0f;

    for (int base = beg; base < end; base += 64) {
        const int lim = min(end - base, 64);
        int myIdx = 0;
        if (lane < lim) myIdx = esrc[base + lane];     // one coalesced load / 64 edges
        for (int i0 = 0; i0 < lim; i0 += 16) {
            uint4 v[4];
#pragma unroll
            for (int u = 0; u < 4; ++u) {
                int slot = i0 + u * 4 + g;
                int s = __shfl(myIdx, slot, 64);
                v[u] = make_uint4(0u, 0u, 0u, 0u);
                if (slot < lim)
                    v[u] = *(const uint4*)(fb + ((size_t)s << 8) + c * 16);
            }
#pragma unroll
            for (int u = 0; u < 4; ++u) {
                acc[0] += bflo(v[u].x);
                acc[1] += bfhi(v[u].x);
                acc[2] += bflo(v[u].y);
                acc[3] += bfhi(v[u].y);
                acc[4] += bflo(v[u].z);
                acc[5] += bfhi(v[u].z);
                acc[6] += bflo(v[u].w);
                acc[7] += bfhi(v[u].w);
            }
        }
    }
#pragma unroll
    for (int r = 0; r < 8; ++r) {
        acc[r] += __shfl_xor(acc[r], 16, 64);
        acc[r] += __shfl_xor(acc[r], 32, 64);
    }
    if (g == 0) {
        const int dg = end - beg;
        const float inv = (dg > 0) ? 1.0f / (float)dg : 0.0f;
        union { ushort u[8]; uint4 v; } p;
#pragma unroll
        for (int r = 0; r < 8; ++r) p.u[r] = f2bf(acc[r] * inv);
        *(uint4*)((char*)mean + ((size_t)node << 8) + c * 16) = p.v;
    }
}

// -------- fused MFMA: out = relu( [mean|feat](bf16) @ Wb^T + b ) --------
// Block: 256 threads (4 waves), tile 64 nodes x 128 outs, K = 256.
// Wave w owns cols [w*32, w*32+32): acc[4 mfrag][2 nfrag].
// A staged in LDS bf16, XOR-swizzled: byte ^= (row&7)<<4.
template <int OUT_BF16>
__global__ __launch_bounds__(256) void sage_mfma(const ushort* __restrict__ feat,
                                                 const ushort* __restrict__ mean,
                                                 const ushort* __restrict__ Wb,
                                                 const float* __restrict__ bias,
                                                 void* __restrict__ outv) {
    __shared__ __align__(16) char As[64 * 512];   // 64 rows x 256 bf16, swizzled

    const int tid = threadIdx.x;
    const int nodeBase = blockIdx.x * 64;

    // ---- stage: bf16 rows -> swizzled LDS ----
    {
        const int row = tid >> 2;          // 0..63
        const int q = tid & 3;             // 128-byte quarter of the 512B row
        const int node = nodeBase + row;
        const bool valid = node < N_NODES;
        const ushort* srcp = (q < 2) ? (mean + (size_t)node * D + q * 64)
                                     : (feat + (size_t)node * D + (q - 2) * 64);
        const int swz = (row & 7) << 4;
#pragma unroll
        for (int c = 0; c < 8; ++c) {      // 8 chunks of 16 B
            uint4 v = make_uint4(0u, 0u, 0u, 0u);
            if (valid) v = *(const uint4*)(srcp + c * 8);
            int colb = q * 128 + c * 16;   // byte col
            *(uint4*)(As + row * 512 + (colb ^ swz)) = v;
        }
    }
    __syncthreads();

    // ---- MFMA main loop ----
    const int lane = tid & 63;
    const int w = tid >> 6;            // wave id: col slice w*32
    const int l15 = lane & 15;
    const int lg = lane >> 4;          // k-group
    const int swz = (l15 & 7) << 4;

    f32x4 acc[4][2];
#pragma unroll
    for (int m = 0; m < 4; ++m) {
        acc[m][0] = (f32x4)(0.0f);
        acc[m][1] = (f32x4)(0.0f);
    }

    const ushort* WA = Wb + (size_t)(w * 32 + l15) * 256 + lg * 8;
    const ushort* WB = WA + 16 * 256;

#pragma unroll
    for (int t = 0; t < 8; ++t) {      // k0 = t*32
        bf16x8 b0 = *(const bf16x8*)(WA + t * 32);
        bf16x8 b1 = *(const bf16x8*)(WB + t * 32);
        const int kb = t * 64 + lg * 16;                   // byte col base
#pragma unroll
        for (int m = 0; m < 4; ++m) {
            bf16x8 a = *(const bf16x8*)(As + (m * 16 + l15) * 512 + (kb ^ swz));
            acc[m][0] = __builtin_amdgcn_mfma_f32_16x16x32_bf16(a, b0, acc[m][0], 0, 0, 0);
            acc[m][1] = __builtin_amdgcn_mfma_f32_16x16x32_bf16(a, b1, acc[m][1], 0, 0, 0);
        }
    }

    // ---- epilogue: bias + relu + store ----
    const int c0 = w * 32 + l15;
    const float bv0 = bias[c0];
    const float bv1 = bias[c0 + 16];
#pragma unroll
    for (int m = 0; m < 4; ++m) {
#pragma unroll
        for (int j = 0; j < 4; ++j) {
            int node = nodeBase + m * 16 + lg * 4 + j;
            if (node < N_NODES) {
                float r0 = fmaxf(acc[m][0][j] + bv0, 0.0f);
                float r1 = fmaxf(acc[m][1][j] + bv1, 0.0f);
                if (OUT_BF16) {
                    ushort* out = (ushort*)outv;
                    out[(size_t)node * D + c0]      = f2bf(r0);
                    out[(size_t)node * D + c0 + 16] = f2bf(r1);
                } else {
                    float* out = (float*)outv;
                    out[(size_t)node * D + c0]      = r0;
                    out[(size_t)node * D + c0 + 16] = r1;
                }
            }
        }
    }
}

extern "C" void kernel_launch(void* const* d_in, const int* in_sizes, int n_in,
                              void* d_out, int out_size, void* d_ws, size_t ws_size,
                              hipStream_t stream) {
    const float* x   = (const float*)d_in[0];
    const int*   ei  = (const int*)d_in[1];   // jax x64 disabled -> int32
    const int*   src = ei;
    const int*   dst = ei + N_EDGES;
    const float* W1l = (const float*)d_in[2];
    const float* b1  = (const float*)d_in[3];
    const float* W1r = (const float*)d_in[4];
    const float* W2l = (const float*)d_in[5];
    const float* b2  = (const float*)d_in[6];
    const float* W2r = (const float*)d_in[7];
    float* out = (float*)d_out;

    ushort* xb     = (ushort*)d_ws;                        // N*D bf16
    ushort* hb     = xb + (size_t)N_NODES * D;             // N*D bf16
    ushort* meanb  = hb + (size_t)N_NODES * D;             // N*D bf16
    int*   row_off = (int*)(meanb + (size_t)N_NODES * D);  // N+1
    int*   esrc    = row_off + (N_NODES + 1);              // E
    int*   rank    = esrc + N_EDGES;                       // E
    int*   deg8    = rank + N_EDGES;                       // 8*PSTRIDE
    int*   cursor8 = deg8 + 8 * PSTRIDE;                   // 8*PSTRIDE
    int*   incl    = cursor8 + 8 * PSTRIDE;                // N
    int*   blockSum= incl + N_NODES;                       // SCAN_BLK
    ushort* Wb1    = (ushort*)(blockSum + SCAN_BLK);       // 128*256 bf16
    ushort* Wb2    = Wb1 + 128 * 256;                      // 128*256 bf16

    const int edge4Blocks = N_EDGES / 1024;                // 625 exact
    const int waveBlocks = (N_NODES * 64 + 255) / 256;     // 12500
    const int gemmBlocks = (N_NODES + 63) / 64;            // 782
    const int prepBlocks = 625 + 3125 + 256;               // 4006
    const int zeroBlocks = (8 * PSTRIDE * 4) / 4096;       // 391 exact (16B/thread)

    // ---- CSR build + converts (once; shared by both layers) ----
    zero_kernel<<<zeroBlocks, 256, 0, stream>>>((uint4*)deg8);
    prep_kernel<<<prepBlocks, 256, 0, stream>>>(x, W1l, W1r, W2l, W2r, dst,
                                                xb, Wb1, Wb2, deg8, rank);
    scan1_kernel<<<SCAN_BLK, 256, 0, stream>>>(deg8, incl, blockSum);
    scan2_kernel<<<SCAN_BLK, 256, 0, stream>>>(deg8, incl, blockSum, row_off, cursor8);
    fill_kernel<<<edge4Blocks, 256, 0, stream>>>(src, dst, rank, cursor8, esrc);

    // ---- layer 1 ----
    gather_mean<<<waveBlocks, 256, 0, stream>>>(row_off, esrc, xb, meanb);
    sage_mfma<1><<<gemmBlocks, 256, 0, stream>>>(xb, meanb, Wb1, b1, hb);

    // ---- layer 2 ----
    gather_mean<<<waveBlocks, 256, 0, stream>>>(row_off, esrc, hb, meanb);
    sage_mfma<0><<<gemmBlocks, 256, 0, stream>>>(hb, meanb, Wb2, b2, out);
}